// Round 1
// 469.801 us; speedup vs baseline: 1.0142x; 1.0142x over previous
//
#include <hip/hip_runtime.h>
#include <math.h>

#define N_EMB   1000000
#define D       64
#define E_PAIRS 65536
#define K_NEG   16
#define P_TOTAL (E_PAIRS * (K_NEG + 1))   /* 1114112 */
#define PPB     128                        /* pairs per block (4 waves x 32 pairs) */

typedef __attribute__((ext_vector_type(8))) short  short8;
typedef __attribute__((ext_vector_type(4))) float  float4v;

static __device__ __forceinline__ unsigned short f2bf(float f) {
    unsigned int x = __float_as_uint(f);
    unsigned int r = (x + 0x7fffu + ((x >> 16) & 1u)) >> 16;   // RNE
    return (unsigned short)r;
}

static __device__ __forceinline__ short8 pack8(float4 a, float4 b) {
    short8 r;
    r[0] = (short)f2bf(a.x); r[1] = (short)f2bf(a.y);
    r[2] = (short)f2bf(a.z); r[3] = (short)f2bf(a.w);
    r[4] = (short)f2bf(b.x); r[5] = (short)f2bf(b.y);
    r[6] = (short)f2bf(b.z); r[7] = (short)f2bf(b.w);
    return r;
}

static __device__ __forceinline__ float4 mul4(float4 a, float4 b) {
    return make_float4(a.x * b.x, a.y * b.y, a.z * b.z, a.w * b.w);
}

// Gather one pair's (u,v) rows straight into the 6 MFMA A-fragments for this lane.
// Lane needs elements k = quad*8 + [0..8) of each 32-wide k-slice:
//   ks0: u[q8..q8+8)      ks1: u[32+q8..)      ks2: v[q8..)   ks3: v[32+q8..)
//   ks4: (u*v)[q8..)      ks5: (u*v)[32+q8..)
// All loads are 16B-aligned float4 within the 256B row; the wave's 16 pairs x 4 quads
// fully consume every touched cache line.
static __device__ __forceinline__ void load_frags(const float* __restrict__ embeds,
                                                  int ui, int vi, int quad,
                                                  short8* fr)
{
    const float* up = embeds + (long long)ui * D + quad * 8;
    const float* vp = embeds + (long long)vi * D + quad * 8;
    float4 ua = *(const float4*)(up);
    float4 ub = *(const float4*)(up + 4);
    float4 uc = *(const float4*)(up + 32);
    float4 ud = *(const float4*)(up + 36);
    float4 va = *(const float4*)(vp);
    float4 vb = *(const float4*)(vp + 4);
    float4 vc = *(const float4*)(vp + 32);
    float4 vd = *(const float4*)(vp + 36);
    fr[0] = pack8(ua, ub);
    fr[1] = pack8(uc, ud);
    fr[2] = pack8(va, vb);
    fr[3] = pack8(vc, vd);
    fr[4] = pack8(mul4(ua, va), mul4(ub, vb));
    fr[5] = pack8(mul4(uc, vc), mul4(ud, vd));
}

__global__ __launch_bounds__(256)
void prep_kernel(const float* __restrict__ W1, unsigned short* __restrict__ W1bf)
{
    int i = blockIdx.x * 256 + threadIdx.x;
    if (i < 64 * 192) W1bf[i] = f2bf(W1[i]);
}

// Zero LDS, zero barriers: each wave owns 32 pairs (2 m-tiles), gathers its
// A-fragments directly to registers, MFMAs against W1bf (24KB, L1/L2-resident).
// __launch_bounds__(256,4) caps VGPR at 128 -> 16 waves/CU, waves free-run.
__global__ __launch_bounds__(256, 4)
void score_kernel(const float* __restrict__ embeds,
                  const int*   __restrict__ pos,
                  const int*   __restrict__ neg,
                  const unsigned short* __restrict__ W1bf,
                  const float* __restrict__ b1,
                  const float* __restrict__ W2,
                  const float* __restrict__ b2,
                  float*       __restrict__ scores)
{
    const int t    = threadIdx.x;
    const int lane = t & 63;
    const int wave = t >> 6;
    const int c16  = lane & 15;
    const int quad = lane >> 4;
    const int pw   = blockIdx.x * PPB + wave * 32;   // this wave's 32 pairs

    // ---- pair indices (wave-uniform pos/neg branch: E_PAIRS % 32 == 0) ----
    const int p0 = pw + c16;
    const int p1 = pw + 16 + c16;
    int2 i0, i1;
    if (pw < E_PAIRS) {
        i0 = ((const int2*)pos)[p0];
        i1 = ((const int2*)pos)[p1];
    } else {
        i0 = ((const int2*)neg)[p0 - E_PAIRS];
        i1 = ((const int2*)neg)[p1 - E_PAIRS];
    }

    // ---- gather A-fragments for both m-tiles straight into registers ----
    short8 a0[6], a1[6];
    load_frags(embeds, i0.x, i0.y, quad, a0);
    load_frags(embeds, i1.x, i1.y, quad, a1);

    // ---- MFMA: 2 m-tiles x 4 n-tiles, K=192 (6 steps of 32) ----
    float4v acc[2][4];
    #pragma unroll
    for (int mt = 0; mt < 2; ++mt)
        #pragma unroll
        for (int nt = 0; nt < 4; ++nt)
            acc[mt][nt] = (float4v){0.f, 0.f, 0.f, 0.f};

    #pragma unroll
    for (int ks = 0; ks < 6; ++ks) {
        const int koff = ks * 32 + quad * 8;
        short8 bfrag[4];
        #pragma unroll
        for (int nt = 0; nt < 4; ++nt)
            bfrag[nt] = *(const short8*)(W1bf + (nt * 16 + c16) * 192 + koff);
        #pragma unroll
        for (int nt = 0; nt < 4; ++nt) {
            acc[0][nt] = __builtin_amdgcn_mfma_f32_16x16x32_bf16(a0[ks], bfrag[nt], acc[0][nt], 0, 0, 0);
            acc[1][nt] = __builtin_amdgcn_mfma_f32_16x16x32_bf16(a1[ks], bfrag[nt], acc[1][nt], 0, 0, 0);
        }
    }

    // ---- epilogue: +b1, relu, dot W2, reduce over 16 n-lanes, sigmoid -> exp ----
    float b1v[4], w2v[4];
    #pragma unroll
    for (int nt = 0; nt < 4; ++nt) {
        b1v[nt] = b1[nt * 16 + c16];
        w2v[nt] = W2[nt * 16 + c16];
    }
    const float b2v = b2[0];

    #pragma unroll
    for (int mt = 0; mt < 2; ++mt) {
        #pragma unroll
        for (int reg = 0; reg < 4; ++reg) {
            float s = 0.f;
            #pragma unroll
            for (int nt = 0; nt < 4; ++nt) {
                float h = acc[mt][nt][reg] + b1v[nt];
                s += (h > 0.f ? h : 0.f) * w2v[nt];
            }
            s += __shfl_xor(s, 1);
            s += __shfl_xor(s, 2);
            s += __shfl_xor(s, 4);
            s += __shfl_xor(s, 8);
            if (c16 == 0) {
                float sig = 1.f / (1.f + expf(-(s + b2v)));
                scores[pw + mt * 16 + quad * 4 + reg] = expf(sig);
            }
        }
    }
}

__global__ __launch_bounds__(256)
void reduce_kernel(const float* __restrict__ scores, float* __restrict__ partials)
{
    __shared__ float sdata[256];
    int e = blockIdx.x * 256 + threadIdx.x;    // e in [0, E_PAIRS)
    float pos_s = scores[e];
    const float* ns = scores + E_PAIRS + (size_t)e * K_NEG;
    float nsum = 0.f;
    #pragma unroll
    for (int c = 0; c < 4; ++c) {
        float4 v = *(const float4*)(ns + c * 4);
        nsum += v.x + v.y + v.z + v.w;
    }
    float term = pos_s / (pos_s + nsum + 1e-8f) + 1e-8f;
    sdata[threadIdx.x] = term;
    __syncthreads();
    for (int s = 128; s > 0; s >>= 1) {
        if (threadIdx.x < s) sdata[threadIdx.x] += sdata[threadIdx.x + s];
        __syncthreads();
    }
    if (threadIdx.x == 0) partials[blockIdx.x] = sdata[0];
}

__global__ __launch_bounds__(256)
void final_kernel(const float* __restrict__ partials, float* __restrict__ out)
{
    __shared__ float sdata[256];
    sdata[threadIdx.x] = partials[threadIdx.x];
    __syncthreads();
    for (int s = 128; s > 0; s >>= 1) {
        if (threadIdx.x < s) sdata[threadIdx.x] += sdata[threadIdx.x + s];
        __syncthreads();
    }
    if (threadIdx.x == 0) out[0] = -sdata[0];
}

extern "C" void kernel_launch(void* const* d_in, const int* in_sizes, int n_in,
                              void* d_out, int out_size, void* d_ws, size_t ws_size,
                              hipStream_t stream)
{
    const float* embeds = (const float*)d_in[0];
    const int*   pos    = (const int*)d_in[1];
    const int*   neg    = (const int*)d_in[2];
    const float* W1     = (const float*)d_in[3];
    const float* b1     = (const float*)d_in[4];
    const float* W2     = (const float*)d_in[5];
    const float* b2     = (const float*)d_in[6];
    float* out = (float*)d_out;

    float* scores   = (float*)d_ws;                           // P_TOTAL floats
    float* partials = scores + P_TOTAL;                       // 256 floats
    unsigned short* W1bf = (unsigned short*)(partials + 256); // 64*192 bf16

    prep_kernel<<<48, 256, 0, stream>>>(W1, W1bf);
    score_kernel<<<P_TOTAL / PPB, 256, 0, stream>>>(embeds, pos, neg, W1bf, b1, W2, b2, scores);
    reduce_kernel<<<E_PAIRS / 256, 256, 0, stream>>>(scores, partials);
    final_kernel<<<1, 256, 0, stream>>>(partials, out);
}